// Round 6
// baseline (1206.404 us; speedup 1.0000x reference)
//
#include <hip/hip_runtime.h>

typedef unsigned short u16;
typedef unsigned int u32;
typedef __bf16 bf16x8 __attribute__((ext_vector_type(8)));
typedef bf16x8 __attribute__((may_alias)) bf16x8a;   // TBAA-safe vector loads
typedef float f32x4 __attribute__((ext_vector_type(4)));
typedef _Float16 f16;
typedef _Float16 f16x2 __attribute__((ext_vector_type(2)));

#define BB 32
#define SS 1024
#define HH 128
#define DD 256

__device__ __forceinline__ float b2f(u16 u) {
    u32 v = ((u32)u) << 16;
    return __builtin_bit_cast(float, v);
}
__device__ __forceinline__ u16 f2b(float f) {
    u32 u = __builtin_bit_cast(u32, f);
    u32 r = (u + 0x7fffu + ((u >> 16) & 1u)) >> 16;   // RNE
    return (u16)r;
}
__device__ __forceinline__ float sig_fast(float x) {
    return __builtin_amdgcn_rcpf(1.0f + __builtin_amdgcn_exp2f(-1.4426950408889634f * x));
}
__device__ __forceinline__ float tanh_fast(float x) {
    return 2.0f * sig_fast(2.0f * x) - 1.0f;
}

// ---------------------------------------------------------------------------
// fp32 -> bf16 conversion for x (grid-stride, float4 / ushort4)
// ---------------------------------------------------------------------------
__global__ __launch_bounds__(256) void conv_f32_bf16(
    const float* __restrict__ src, u16* __restrict__ dst, int n4)
{
    for (int i = blockIdx.x * 256 + threadIdx.x; i < n4; i += gridDim.x * 256) {
        float4 v = ((const float4*)src)[i];
        ushort4 o;
        o.x = f2b(v.x); o.y = f2b(v.y); o.z = f2b(v.z); o.w = f2b(v.w);
        ((ushort4*)dst)[i] = o;
    }
}

// ---------------------------------------------------------------------------
// All 7 weight conversions in ONE kernel (each matrix = 65536 elements).
// mode 0: gate-perm (row g*128+u -> u*4+g), bf16   (Wih for xg GEMM)
// mode 1: gate-perm, f16                           (Whh for scan dot2)
// mode 2: plain, bf16                              (Wq/Wk/Wv)
// ---------------------------------------------------------------------------
__global__ __launch_bounds__(256) void conv_weights(
    const float* __restrict__ fwWih, const float* __restrict__ bwWih,
    const float* __restrict__ fwWhh, const float* __restrict__ bwWhh,
    const float* __restrict__ Wq, const float* __restrict__ Wk,
    const float* __restrict__ Wv,
    u16* __restrict__ wfih, u16* __restrict__ wbih, u16* __restrict__ whhf,
    u16* __restrict__ wq, u16* __restrict__ wk, u16* __restrict__ wv)
{
    const int which = blockIdx.y;
    const float* src; u16* dst; int mode;
    switch (which) {
        case 0: src = fwWih; dst = wfih;              mode = 0; break;
        case 1: src = bwWih; dst = wbih;              mode = 0; break;
        case 2: src = fwWhh; dst = whhf;              mode = 1; break;
        case 3: src = bwWhh; dst = whhf + 512 * 128;  mode = 1; break;
        case 4: src = Wq;    dst = wq;                mode = 2; break;
        case 5: src = Wk;    dst = wk;                mode = 2; break;
        default: src = Wv;   dst = wv;                mode = 2; break;
    }
    for (int i = blockIdx.x * 256 + threadIdx.x; i < 65536 / 4; i += 32 * 256) {
        float4 v = ((const float4*)src)[i];
        ushort4 o;
        if (mode == 1) {
            o.x = __builtin_bit_cast(u16, (f16)v.x);
            o.y = __builtin_bit_cast(u16, (f16)v.y);
            o.z = __builtin_bit_cast(u16, (f16)v.z);
            o.w = __builtin_bit_cast(u16, (f16)v.w);
        } else {
            o.x = f2b(v.x); o.y = f2b(v.y); o.z = f2b(v.z); o.w = f2b(v.w);
        }
        if (mode == 2) {
            ((ushort4*)dst)[i] = o;
        } else {
            int r = i >> 5, c4 = i & 31;                 // [512][128] view
            int rp = ((r & 127) << 2) | (r >> 7);        // u*4 + g
            *(ushort4*)&dst[rp * 128 + c4 * 4] = o;
        }
    }
}

// ---------------------------------------------------------------------------
// Shared MFMA GEMM core: C[M,N] = A[M,K]*Bt[N,K]^T, bf16 in, fp32 acc, bf16
// out. 128x128 tile, BK=64, 256 thr = 4 waves (2x2), wave = 64x64.
// MODE 0: row-major store, no bias. MODE 1: xg store [s][b][col] + bias
// (bias index un-permuted since cols are gate-interleaved).
// ---------------------------------------------------------------------------
template <int MODE>
__device__ __forceinline__ void gemm_core(
    const u16* __restrict__ A, const u16* __restrict__ Bt,
    const float* __restrict__ bias1, const float* __restrict__ bias2,
    u16* __restrict__ Cout, int K, int N)
{
    __shared__ u16 As[128 * 72];
    __shared__ u16 Bs[128 * 72];
    const int tid = threadIdx.x;
    const int lane = tid & 63, wave = tid >> 6;
    const int wm = wave >> 1, wn = wave & 1;
    const int lo = lane & 15, hi = lane >> 4;
    const int m0 = blockIdx.x * 128, n0 = blockIdx.y * 128;

    f32x4 acc[4][4] = {};

    for (int k0 = 0; k0 < K; k0 += 64) {
        __syncthreads();
#pragma unroll
        for (int i = 0; i < 4; i++) {
            int c = tid + 256 * i;
            int row = c >> 3, kc = (c & 7) * 8;
            *(uint4*)&As[row * 72 + kc] =
                *(const uint4*)&A[(size_t)(m0 + row) * K + k0 + kc];
            *(uint4*)&Bs[row * 72 + kc] =
                *(const uint4*)&Bt[(size_t)(n0 + row) * K + k0 + kc];
        }
        __syncthreads();
#pragma unroll
        for (int ks = 0; ks < 2; ks++) {
            bf16x8 af[4], bfr[4];
#pragma unroll
            for (int i = 0; i < 4; i++)
                af[i] = *(const bf16x8a*)&As[(wm * 64 + i * 16 + lo) * 72 + ks * 32 + hi * 8];
#pragma unroll
            for (int j = 0; j < 4; j++)
                bfr[j] = *(const bf16x8a*)&Bs[(wn * 64 + j * 16 + lo) * 72 + ks * 32 + hi * 8];
#pragma unroll
            for (int i = 0; i < 4; i++)
#pragma unroll
                for (int j = 0; j < 4; j++)
                    acc[i][j] = __builtin_amdgcn_mfma_f32_16x16x32_bf16(
                        af[i], bfr[j], acc[i][j], 0, 0, 0);
        }
    }
#pragma unroll
    for (int j = 0; j < 4; j++) {
        int col = n0 + wn * 64 + j * 16 + lo;
        float bsum = 0.f;
        if (MODE == 1) {
            int co = ((col & 3) << 7) | (col >> 2);   // un-permute for bias lookup
            bsum = bias1[co] + bias2[co];
        }
#pragma unroll
        for (int i = 0; i < 4; i++) {
            int row0 = m0 + wm * 64 + i * 16 + hi * 4;
#pragma unroll
            for (int r = 0; r < 4; r++) {
                float v = acc[i][j][r] + bsum;
                if (MODE == 1) {
                    int row = row0 + r;                 // = b*1024 + s
                    int sidx = row & 1023, bidx = row >> 10;
                    Cout[(size_t)sidx * (BB * 512) + bidx * 512 + col] = f2b(v);
                } else {
                    Cout[(size_t)(row0 + r) * N + col] = f2b(v);
                }
            }
        }
    }
}

// both xg directions in one launch (blockIdx.z = dir)
__global__ __launch_bounds__(256) void gemm_xg(
    const u16* __restrict__ A, const u16* __restrict__ Bt_f,
    const u16* __restrict__ Bt_b,
    const float* __restrict__ f_bih, const float* __restrict__ f_bhh,
    const float* __restrict__ b_bih, const float* __restrict__ b_bhh,
    u16* __restrict__ xg)
{
    const int dir = blockIdx.z;
    gemm_core<1>(A, dir ? Bt_b : Bt_f,
                 dir ? b_bih : f_bih, dir ? b_bhh : f_bhh,
                 xg + (size_t)dir * SS * BB * 512, 128, 512);
}

// q,k,v in one launch (blockIdx.z selects)
__global__ __launch_bounds__(256) void gemm_qkv(
    const u16* __restrict__ A, const u16* __restrict__ Wq,
    const u16* __restrict__ Wk, const u16* __restrict__ Wv,
    u16* __restrict__ qb, u16* __restrict__ kb, u16* __restrict__ vb)
{
    const int z = blockIdx.z;
    const u16* Bt = (z == 0) ? Wq : (z == 1) ? Wk : Wv;
    u16* out = (z == 0) ? qb : (z == 1) ? kb : vb;
    gemm_core<0>(A, Bt, nullptr, nullptr, out, 256, 256);
}

// ---------------------------------------------------------------------------
// dot2 LSTM scan, split-K + 2-seq interleave. 32 WGs x 256 thr (4 waves).
// WG: dir = wg>>4; sequences (dir, b0) and (dir, b0+16) share Whh registers.
// Thread t: unit u = t>>1 (owns ALL 4 gate rows 4u..4u+3 -> no gate
// exchange), K-half kh = t&1 (h reads halved; 4 shfl_xor(1) reduces).
// Weights: 4 rows x 64 f16 = 128 VGPRs. h in LDS f16, double-buffered,
// 1 barrier/step. Two independent chains (A/B) interleave VALU & LDS.
// ---------------------------------------------------------------------------
__global__ __launch_bounds__(256, 1) void lstm_scan_dot2x2(
    const u16* __restrict__ Whh_h,   // [2][512][128] f16, rows permuted
    const u16* __restrict__ xg,      // [2][S][B][512] bf16, cols permuted
    u16* __restrict__ hout)          // [B][S][256] bf16
{
    const int wg = blockIdx.x;       // 0..31
    const int dir = wg >> 4;
    const int b0 = wg & 15;
    const int t_ = threadIdx.x;
    const int u = t_ >> 1;           // unit 0..127
    const int kh = t_ & 1;           // K-half

    // resident weights: gate rows 4u..4u+3, K-half kh (32 u32 each)
    u32 w[4][32];
    {
        const u16* wb = Whh_h + (size_t)dir * 512 * 128 + 64 * kh;
#pragma unroll
        for (int g = 0; g < 4; g++) {
            const uint4* p = (const uint4*)(wb + (size_t)(4 * u + g) * 128);
#pragma unroll
            for (int i = 0; i < 8; i++) {
                uint4 a = p[i];
                w[g][4 * i + 0] = a.x; w[g][4 * i + 1] = a.y;
                w[g][4 * i + 2] = a.z; w[g][4 * i + 3] = a.w;
            }
        }
    }

    __shared__ __align__(16) u16 hbuf[2][2][128];   // [seq][buf][unit] f16
    if (t_ < 128) { hbuf[0][0][t_] = 0; hbuf[1][0][t_] = 0; }
    float cA = 0.f, cB = 0.f;

    const u16* xgd = xg + (size_t)dir * SS * (BB * 512) + 4 * u;
    const u16* xgA = xgd + (size_t)b0 * 512;
    const u16* xgB = xgd + (size_t)(b0 + 16) * 512;
    u16* hopA = hout + (size_t)b0 * SS * DD + dir * HH + u;
    u16* hopB = hout + (size_t)(b0 + 16) * SS * DD + dir * HH + u;

    int s = dir ? (SS - 1) : 0;
    const int dstep = dir ? -1 : 1;
    uint2 nxA = *(const uint2*)&xgA[(size_t)s * (BB * 512)];
    uint2 nxB = *(const uint2*)&xgB[(size_t)s * (BB * 512)];
    __syncthreads();

    for (int t = 0; t < SS; t++) {
        uint2 xA = nxA, xB = nxB;
        int s_next = s + dstep;
        if (t < SS - 1) {   // prefetch next step (one-step latency hiding)
            nxA = *(const uint2*)&xgA[(size_t)s_next * (BB * 512)];
            nxB = *(const uint2*)&xgB[(size_t)s_next * (BB * 512)];
        }

        const uint4* hA = (const uint4*)&hbuf[0][t & 1][64 * kh];
        const uint4* hBp = (const uint4*)&hbuf[1][t & 1][64 * kh];
        float sA[4] = {0.f, 0.f, 0.f, 0.f};
        float sB[4] = {0.f, 0.f, 0.f, 0.f};
#pragma unroll
        for (int i = 0; i < 8; i++) {
            uint4 ha = hA[i];
            uint4 hb = hBp[i];
            u32 aw[4] = {ha.x, ha.y, ha.z, ha.w};
            u32 bw[4] = {hb.x, hb.y, hb.z, hb.w};
#pragma unroll
            for (int j = 0; j < 4; j++) {
                f16x2 av = __builtin_bit_cast(f16x2, aw[j]);
                f16x2 bv = __builtin_bit_cast(f16x2, bw[j]);
#pragma unroll
                for (int g = 0; g < 4; g++) {
                    f16x2 wv = __builtin_bit_cast(f16x2, w[g][4 * i + j]);
                    sA[g] = __builtin_amdgcn_fdot2(av, wv, sA[g], false);
                    sB[g] = __builtin_amdgcn_fdot2(bv, wv, sB[g], false);
                }
            }
        }
        // cross-half reduce (partner lane has the other K-half)
#pragma unroll
        for (int g = 0; g < 4; g++) {
            sA[g] += __shfl_xor(sA[g], 1, 64);
            sB[g] += __shfl_xor(sB[g], 1, 64);
        }
        // add xg (gates i,f,g~,o = permuted cols 4u..4u+3)
        sA[0] += b2f((u16)(xA.x & 0xffff)); sA[1] += b2f((u16)(xA.x >> 16));
        sA[2] += b2f((u16)(xA.y & 0xffff)); sA[3] += b2f((u16)(xA.y >> 16));
        sB[0] += b2f((u16)(xB.x & 0xffff)); sB[1] += b2f((u16)(xB.x >> 16));
        sB[2] += b2f((u16)(xB.y & 0xffff)); sB[3] += b2f((u16)(xB.y >> 16));

        cA = fmaf(sig_fast(sA[1]), cA, sig_fast(sA[0]) * tanh_fast(sA[2]));
        float hAv = sig_fast(sA[3]) * tanh_fast(cA);
        cB = fmaf(sig_fast(sB[1]), cB, sig_fast(sB[0]) * tanh_fast(sB[2]));
        float hBv = sig_fast(sB[3]) * tanh_fast(cB);

        if (kh == 0) {   // one lane of the pair feeds LDS, the other global
            hbuf[0][(t + 1) & 1][u] = __builtin_bit_cast(u16, (f16)hAv);
            hbuf[1][(t + 1) & 1][u] = __builtin_bit_cast(u16, (f16)hBv);
        } else {
            hopA[(size_t)s * DD] = f2b(hAv);
            hopB[(size_t)s * DD] = f2b(hBv);
        }
        __syncthreads();
        s = s_next;
    }
}

// ---------------------------------------------------------------------------
// V transpose: v[b][s][d] -> vT[b][d][s] via LDS tiles (64x64)
// ---------------------------------------------------------------------------
__global__ __launch_bounds__(256) void transpose_v(
    const u16* __restrict__ v, u16* __restrict__ vT)
{
    __shared__ u16 tile[64 * 72];
    const int b = blockIdx.z, s0 = blockIdx.x * 64, d0 = blockIdx.y * 64;
    const int tid = threadIdx.x;
#pragma unroll
    for (int i = 0; i < 2; i++) {
        int c = tid + 256 * i;
        int sl = c >> 3, dc = (c & 7) * 8;
        *(uint4*)&tile[sl * 72 + dc] =
            *(const uint4*)&v[((size_t)b * SS + s0 + sl) * DD + d0 + dc];
    }
    __syncthreads();
#pragma unroll
    for (int i = 0; i < 2; i++) {
        int c = tid + 256 * i;
        int dl = c >> 3, sc = (c & 7) * 8;
        u32 x0 = (u32)tile[(sc + 0) * 72 + dl] | ((u32)tile[(sc + 1) * 72 + dl] << 16);
        u32 x1 = (u32)tile[(sc + 2) * 72 + dl] | ((u32)tile[(sc + 3) * 72 + dl] << 16);
        u32 x2 = (u32)tile[(sc + 4) * 72 + dl] | ((u32)tile[(sc + 5) * 72 + dl] << 16);
        u32 x3 = (u32)tile[(sc + 6) * 72 + dl] | ((u32)tile[(sc + 7) * 72 + dl] << 16);
        uint4 val; val.x = x0; val.y = x1; val.z = x2; val.w = x3;
        *(uint4*)&vT[((size_t)b * DD + d0 + dl) * SS + s0 + sc] = val;
    }
}

// ---------------------------------------------------------------------------
// Flash attention: WG = (batch, 64-row q tile), 256 thr = 4 waves, each wave
// a 16-row stripe. KV tiles of 32. exp2-domain softmax, scale folded. f32 out.
// ---------------------------------------------------------------------------
__global__ __launch_bounds__(256) void attn_kernel(
    const u16* __restrict__ q, const u16* __restrict__ k,
    const u16* __restrict__ vT, float* __restrict__ out)
{
    __shared__ u16 Ks[32 * 264];
    __shared__ u16 Vs[256 * 40];
    __shared__ u16 Ps[64 * 40];
    const int b = blockIdx.y, q0 = blockIdx.x * 64;
    const int tid = threadIdx.x, wave = tid >> 6, lane = tid & 63;
    const int lo = lane & 15, hi = lane >> 4;
    const float c1 = 0.09016844005556021f;  // log2(e)/16

    bf16x8 qf[8];
    {
        const u16* qp = q + ((size_t)b * SS + q0 + wave * 16 + lo) * DD;
#pragma unroll
        for (int ks = 0; ks < 8; ks++)
            qf[ks] = *(const bf16x8a*)&qp[ks * 32 + hi * 8];
    }
    float m_i[4] = {-1e30f, -1e30f, -1e30f, -1e30f};
    float l_i[4] = {0.f, 0.f, 0.f, 0.f};
    f32x4 o[16] = {};

    for (int t0 = 0; t0 < SS; t0 += 32) {
        __syncthreads();
#pragma unroll
        for (int i = 0; i < 4; i++) {
            int c = tid + 256 * i;
            {
                int row = c >> 5, dc = (c & 31) * 8;
                *(uint4*)&Ks[row * 264 + dc] =
                    *(const uint4*)&k[((size_t)b * SS + t0 + row) * DD + dc];
            }
            {
                int d = c >> 2, sc = (c & 3) * 8;
                *(uint4*)&Vs[d * 40 + sc] =
                    *(const uint4*)&vT[((size_t)b * DD + d) * SS + t0 + sc];
            }
        }
        __syncthreads();

        f32x4 sacc[2] = {};
#pragma unroll
        for (int ks = 0; ks < 8; ks++) {
#pragma unroll
            for (int j = 0; j < 2; j++) {
                bf16x8 bfr = *(const bf16x8a*)&Ks[(j * 16 + lo) * 264 + ks * 32 + hi * 8];
                sacc[j] = __builtin_amdgcn_mfma_f32_16x16x32_bf16(qf[ks], bfr, sacc[j], 0, 0, 0);
            }
        }

        float tt[2][4];
#pragma unroll
        for (int j = 0; j < 2; j++)
#pragma unroll
            for (int r = 0; r < 4; r++) tt[j][r] = sacc[j][r] * c1;
        float rm[4];
#pragma unroll
        for (int r = 0; r < 4; r++) rm[r] = fmaxf(tt[0][r], tt[1][r]);
#pragma unroll
        for (int mm = 1; mm <= 8; mm <<= 1)
#pragma unroll
            for (int r = 0; r < 4; r++) rm[r] = fmaxf(rm[r], __shfl_xor(rm[r], mm, 64));
        float al[4], rs[4];
#pragma unroll
        for (int r = 0; r < 4; r++) {
            float mn = fmaxf(m_i[r], rm[r]);
            al[r] = __builtin_amdgcn_exp2f(m_i[r] - mn);
            m_i[r] = mn;
            rs[r] = 0.f;
        }
#pragma unroll
        for (int j = 0; j < 2; j++)
#pragma unroll
            for (int r = 0; r < 4; r++) {
                float p = __builtin_amdgcn_exp2f(tt[j][r] - m_i[r]);
                rs[r] += p;
                Ps[(wave * 16 + hi * 4 + r) * 40 + j * 16 + lo] = f2b(p);
            }
#pragma unroll
        for (int mm = 1; mm <= 8; mm <<= 1)
#pragma unroll
            for (int r = 0; r < 4; r++) rs[r] += __shfl_xor(rs[r], mm, 64);
#pragma unroll
        for (int r = 0; r < 4; r++) l_i[r] = l_i[r] * al[r] + rs[r];
#pragma unroll
        for (int nt = 0; nt < 16; nt++) {
            o[nt][0] *= al[0]; o[nt][1] *= al[1];
            o[nt][2] *= al[2]; o[nt][3] *= al[3];
        }
        __syncthreads();   // order u16 Ps stores vs vector reload
        bf16x8 pa = *(const bf16x8a*)&Ps[(wave * 16 + lo) * 40 + hi * 8];
#pragma unroll
        for (int nt = 0; nt < 16; nt++) {
            bf16x8 bv = *(const bf16x8a*)&Vs[(nt * 16 + lo) * 40 + hi * 8];
            o[nt] = __builtin_amdgcn_mfma_f32_16x16x32_bf16(pa, bv, o[nt], 0, 0, 0);
        }
    }
    float inv[4];
#pragma unroll
    for (int r = 0; r < 4; r++) inv[r] = __builtin_amdgcn_rcpf(l_i[r]);
#pragma unroll
    for (int nt = 0; nt < 16; nt++)
#pragma unroll
        for (int r = 0; r < 4; r++) {
            int row = q0 + wave * 16 + hi * 4 + r;
            int col = nt * 16 + lo;
            out[((size_t)b * SS + row) * DD + col] = o[nt][r] * inv[r];
        }
}

// ---------------------------------------------------------------------------
extern "C" void kernel_launch(void* const* d_in, const int* in_sizes, int n_in,
                              void* d_out, int out_size, void* d_ws, size_t ws_size,
                              hipStream_t stream)
{
    (void)in_sizes; (void)n_in; (void)out_size;
    const float* x      = (const float*)d_in[0];
    const float* fw_Wih = (const float*)d_in[1];
    const float* fw_Whh = (const float*)d_in[2];
    const float* fw_bih = (const float*)d_in[3];
    const float* fw_bhh = (const float*)d_in[4];
    const float* bw_Wih = (const float*)d_in[5];
    const float* bw_Whh = (const float*)d_in[6];
    const float* bw_bih = (const float*)d_in[7];
    const float* bw_bhh = (const float*)d_in[8];
    const float* Wq = (const float*)d_in[9];
    const float* Wk = (const float*)d_in[10];
    const float* Wv = (const float*)d_in[11];

    // Workspace layout (total 143,523,840 B; ws proven >= 201 MB in r1/r2):
    //   [0, 67108864)    xg bf16 [2][S][B][512], cols gate-interleaved
    //                    (dead after scan; vb aliases)
    //   +67108864        h   bf16 [32768][256]
    //   +83886080        qb   +100663296 kb   +117440512 vT
    //   +134217728       x16 bf16 [32768][128]
    //   +142606336       weights: fwWih_p, bwWih_p, wq, wk, wv (bf16),
    //                    Whh f16 permuted [2][512][128]
    if (ws_size < 143523840ULL) return;

    char* ws = (char*)d_ws;
    u16* xg  = (u16*)ws;
    u16* h   = (u16*)(ws + 67108864);
    u16* qb  = (u16*)(ws + 83886080);
    u16* kb  = (u16*)(ws + 100663296);
    u16* vT  = (u16*)(ws + 117440512);
    u16* x16 = (u16*)(ws + 134217728);
    u16* wfih16 = (u16*)(ws + 142606336);
    u16* wbih16 = (u16*)(ws + 142606336 + 131072);
    u16* wq16   = (u16*)(ws + 142606336 + 262144);
    u16* wk16   = (u16*)(ws + 142606336 + 393216);
    u16* wv16   = (u16*)(ws + 142606336 + 524288);
    u16* whhf16 = (u16*)(ws + 142606336 + 655360);   // [2][512][128] f16
    u16* vb = (u16*)ws;                              // aliases xg (dead after scan)

    conv_f32_bf16<<<1024, 256, 0, stream>>>(x, x16, (BB * SS * HH) / 4);
    conv_weights<<<dim3(32, 7), 256, 0, stream>>>(
        fw_Wih, bw_Wih, fw_Whh, bw_Whh, Wq, Wk, Wv,
        wfih16, wbih16, whhf16, wq16, wk16, wv16);

    // xg = x @ Wih_p^T + biases -> [s][b][512] permuted-col layout (both dirs)
    gemm_xg<<<dim3(256, 4, 2), 256, 0, stream>>>(
        x16, wfih16, wbih16, fw_bih, fw_bhh, bw_bih, bw_bhh, xg);
    // split-K / 2-seq dot2 scan -> h [b][s][256]
    lstm_scan_dot2x2<<<32, 256, 0, stream>>>(whhf16, xg, h);
    // q,k,v projections in one launch
    gemm_qkv<<<dim3(256, 2, 3), 256, 0, stream>>>(h, wq16, wk16, wv16, qb, kb, vb);
    transpose_v<<<dim3(16, 4, 32), 256, 0, stream>>>(vb, vT);
    // fused attention -> out fp32
    attn_kernel<<<dim3(16, 32), 256, 0, stream>>>(qb, kb, vT, (float*)d_out);
}

// Round 7
// 899.332 us; speedup vs baseline: 1.3414x; 1.3414x over previous
//
#include <hip/hip_runtime.h>

typedef unsigned short u16;
typedef unsigned int u32;
typedef __bf16 bf16x8 __attribute__((ext_vector_type(8)));
typedef bf16x8 __attribute__((may_alias)) bf16x8a;   // TBAA-safe vector loads
typedef float f32x4 __attribute__((ext_vector_type(4)));
typedef _Float16 f16;
typedef _Float16 f16x2 __attribute__((ext_vector_type(2)));

#define BB 32
#define SS 1024
#define HH 128
#define DD 256

__device__ __forceinline__ float b2f(u16 u) {
    u32 v = ((u32)u) << 16;
    return __builtin_bit_cast(float, v);
}
__device__ __forceinline__ u16 f2b(float f) {
    u32 u = __builtin_bit_cast(u32, f);
    u32 r = (u + 0x7fffu + ((u >> 16) & 1u)) >> 16;   // RNE
    return (u16)r;
}
__device__ __forceinline__ float sig_fast(float x) {
    return __builtin_amdgcn_rcpf(1.0f + __builtin_amdgcn_exp2f(-1.4426950408889634f * x));
}
__device__ __forceinline__ float tanh_fast(float x) {
    return 2.0f * sig_fast(2.0f * x) - 1.0f;
}

// ---------------------------------------------------------------------------
// All 7 weight conversions in ONE kernel (each matrix = 65536 elements).
// mode 0: gate-perm (row g*128+u -> u*4+g), bf16   (Wih for xg GEMM)
// mode 1: gate-perm, f16                           (Whh for scan dot2)
// mode 2: plain, bf16                              (Wq/Wk/Wv)
// ---------------------------------------------------------------------------
__global__ __launch_bounds__(256) void conv_weights(
    const float* __restrict__ fwWih, const float* __restrict__ bwWih,
    const float* __restrict__ fwWhh, const float* __restrict__ bwWhh,
    const float* __restrict__ Wq, const float* __restrict__ Wk,
    const float* __restrict__ Wv,
    u16* __restrict__ wfih, u16* __restrict__ wbih, u16* __restrict__ whhf,
    u16* __restrict__ wq, u16* __restrict__ wk, u16* __restrict__ wv)
{
    const int which = blockIdx.y;
    const float* src; u16* dst; int mode;
    switch (which) {
        case 0: src = fwWih; dst = wfih;              mode = 0; break;
        case 1: src = bwWih; dst = wbih;              mode = 0; break;
        case 2: src = fwWhh; dst = whhf;              mode = 1; break;
        case 3: src = bwWhh; dst = whhf + 512 * 128;  mode = 1; break;
        case 4: src = Wq;    dst = wq;                mode = 2; break;
        case 5: src = Wk;    dst = wk;                mode = 2; break;
        default: src = Wv;   dst = wv;                mode = 2; break;
    }
    for (int i = blockIdx.x * 256 + threadIdx.x; i < 65536 / 4; i += 32 * 256) {
        float4 v = ((const float4*)src)[i];
        ushort4 o;
        if (mode == 1) {
            o.x = __builtin_bit_cast(u16, (f16)v.x);
            o.y = __builtin_bit_cast(u16, (f16)v.y);
            o.z = __builtin_bit_cast(u16, (f16)v.z);
            o.w = __builtin_bit_cast(u16, (f16)v.w);
        } else {
            o.x = f2b(v.x); o.y = f2b(v.y); o.z = f2b(v.z); o.w = f2b(v.w);
        }
        if (mode == 2) {
            ((ushort4*)dst)[i] = o;
        } else {
            int r = i >> 5, c4 = i & 31;                 // [512][128] view
            int rp = ((r & 127) << 2) | (r >> 7);        // u*4 + g
            *(ushort4*)&dst[rp * 128 + c4 * 4] = o;
        }
    }
}

// ---------------------------------------------------------------------------
// Shared MFMA GEMM core: C[M,N] = A[M,K]*Bt[N,K]^T, fp32 acc, bf16 out.
// 128x128 tile, BK=64, 256 thr = 4 waves (2x2), wave = 64x64.
// AFP32: A is fp32 in global, converted to bf16 during LDS staging.
// MODE 0: row-major store, no bias. MODE 1: xg store [s][b][col] + bias
// (bias index un-permuted since cols are gate-interleaved).
// ---------------------------------------------------------------------------
template <int MODE, int AFP32>
__device__ __forceinline__ void gemm_core(
    const void* __restrict__ Araw, const u16* __restrict__ Bt,
    const float* __restrict__ bias1, const float* __restrict__ bias2,
    u16* __restrict__ Cout, int K, int N)
{
    __shared__ u16 As[128 * 72];
    __shared__ u16 Bs[128 * 72];
    const int tid = threadIdx.x;
    const int lane = tid & 63, wave = tid >> 6;
    const int wm = wave >> 1, wn = wave & 1;
    const int lo = lane & 15, hi = lane >> 4;
    const int m0 = blockIdx.x * 128, n0 = blockIdx.y * 128;

    f32x4 acc[4][4] = {};

    for (int k0 = 0; k0 < K; k0 += 64) {
        __syncthreads();
#pragma unroll
        for (int i = 0; i < 4; i++) {
            int c = tid + 256 * i;
            int row = c >> 3, kc = (c & 7) * 8;
            if (AFP32) {
                const float* ap = (const float*)Araw + (size_t)(m0 + row) * K + k0 + kc;
                float4 v0 = *(const float4*)ap;
                float4 v1 = *(const float4*)(ap + 4);
                uint4 o;
                o.x = (u32)f2b(v0.x) | ((u32)f2b(v0.y) << 16);
                o.y = (u32)f2b(v0.z) | ((u32)f2b(v0.w) << 16);
                o.z = (u32)f2b(v1.x) | ((u32)f2b(v1.y) << 16);
                o.w = (u32)f2b(v1.z) | ((u32)f2b(v1.w) << 16);
                *(uint4*)&As[row * 72 + kc] = o;
            } else {
                *(uint4*)&As[row * 72 + kc] =
                    *(const uint4*)&((const u16*)Araw)[(size_t)(m0 + row) * K + k0 + kc];
            }
            *(uint4*)&Bs[row * 72 + kc] =
                *(const uint4*)&Bt[(size_t)(n0 + row) * K + k0 + kc];
        }
        __syncthreads();
#pragma unroll
        for (int ks = 0; ks < 2; ks++) {
            bf16x8 af[4], bfr[4];
#pragma unroll
            for (int i = 0; i < 4; i++)
                af[i] = *(const bf16x8a*)&As[(wm * 64 + i * 16 + lo) * 72 + ks * 32 + hi * 8];
#pragma unroll
            for (int j = 0; j < 4; j++)
                bfr[j] = *(const bf16x8a*)&Bs[(wn * 64 + j * 16 + lo) * 72 + ks * 32 + hi * 8];
#pragma unroll
            for (int i = 0; i < 4; i++)
#pragma unroll
                for (int j = 0; j < 4; j++)
                    acc[i][j] = __builtin_amdgcn_mfma_f32_16x16x32_bf16(
                        af[i], bfr[j], acc[i][j], 0, 0, 0);
        }
    }
#pragma unroll
    for (int j = 0; j < 4; j++) {
        int col = n0 + wn * 64 + j * 16 + lo;
        float bsum = 0.f;
        if (MODE == 1) {
            int co = ((col & 3) << 7) | (col >> 2);   // un-permute for bias lookup
            bsum = bias1[co] + bias2[co];
        }
#pragma unroll
        for (int i = 0; i < 4; i++) {
            int row0 = m0 + wm * 64 + i * 16 + hi * 4;
#pragma unroll
            for (int r = 0; r < 4; r++) {
                float v = acc[i][j][r] + bsum;
                if (MODE == 1) {
                    int row = row0 + r;                 // = b*1024 + s
                    int sidx = row & 1023, bidx = row >> 10;
                    Cout[(size_t)sidx * (BB * 512) + bidx * 512 + col] = f2b(v);
                } else {
                    Cout[(size_t)(row0 + r) * N + col] = f2b(v);
                }
            }
        }
    }
}

// both xg directions in one launch (blockIdx.z = dir); A = x in fp32
__global__ __launch_bounds__(256) void gemm_xg(
    const float* __restrict__ A, const u16* __restrict__ Bt_f,
    const u16* __restrict__ Bt_b,
    const float* __restrict__ f_bih, const float* __restrict__ f_bhh,
    const float* __restrict__ b_bih, const float* __restrict__ b_bhh,
    u16* __restrict__ xg)
{
    const int dir = blockIdx.z;
    gemm_core<1, 1>(A, dir ? Bt_b : Bt_f,
                    dir ? b_bih : f_bih, dir ? b_bhh : f_bhh,
                    xg + (size_t)dir * SS * BB * 512, 128, 512);
}

// q,k,v in one launch (blockIdx.z selects)
__global__ __launch_bounds__(256) void gemm_qkv(
    const u16* __restrict__ A, const u16* __restrict__ Wq,
    const u16* __restrict__ Wk, const u16* __restrict__ Wv,
    u16* __restrict__ qb, u16* __restrict__ kb, u16* __restrict__ vb)
{
    const int z = blockIdx.z;
    const u16* Bt = (z == 0) ? Wq : (z == 1) ? Wk : Wv;
    u16* out = (z == 0) ? qb : (z == 1) ? kb : vb;
    gemm_core<0, 0>(A, Bt, nullptr, nullptr, out, 256, 256);
}

// ---------------------------------------------------------------------------
// dot2 LSTM scan: 64 WGs (one per (dir,b) sequence), 512 threads = 8 waves
// (2/SIMD for stall hiding). Thread t owns PERMUTED gate row t (unit u=t>>2,
// gate g=t&3): 128 f16 weights resident as 64 u32 VGPRs. h in LDS f16[128]
// (256 B, double-buffered): 16 broadcast ds_read_b128/thread, 64 fdot2 in 4
// rotating chains. Quad butterfly (3 shfl) gathers the 4 gate sums into the
// g==0 lane, which holds c and writes h (LDS f16 + global bf16). One barrier
// per step.
// ---------------------------------------------------------------------------
__global__ __launch_bounds__(512, 2) void lstm_scan_512(
    const u16* __restrict__ Whh_h,   // [2][512][128] f16, rows permuted
    const u16* __restrict__ xg,      // [2][S][B][512] bf16, cols permuted
    u16* __restrict__ hout)          // [B][S][256] bf16
{
    const int wg = blockIdx.x;       // 0..63
    const int dir = wg >> 5, b = wg & 31;
    const int t_ = threadIdx.x;      // 0..511 = permuted gate row
    const int u = t_ >> 2, g = t_ & 3;

    // resident weights: permuted row t_ = 128 f16 = 64 u32
    u32 w[64];
    {
        const uint4* wp = (const uint4*)(Whh_h + (size_t)dir * 512 * 128 + (size_t)t_ * 128);
#pragma unroll
        for (int i = 0; i < 16; i++) {
            uint4 a = wp[i];
            w[4 * i + 0] = a.x; w[4 * i + 1] = a.y;
            w[4 * i + 2] = a.z; w[4 * i + 3] = a.w;
        }
    }

    __shared__ __align__(16) u16 hbuf[2][128];   // f16 bits, double-buffered
    if (t_ < 128) hbuf[0][t_] = 0;
    float c = 0.0f;

    const u16* xgp = xg + (size_t)dir * SS * (BB * 512) + (size_t)b * 512 + t_;
    u16* hop = hout + (size_t)b * SS * DD + dir * HH + u;

    int s = dir ? (SS - 1) : 0;
    const int dstep = dir ? -1 : 1;
    u16 xnext = xgp[(size_t)s * (BB * 512)];
    __syncthreads();

    for (int t = 0; t < SS; t++) {
        float xv = b2f(xnext);
        int s_next = s + dstep;
        if (t < SS - 1)
            xnext = xgp[(size_t)s_next * (BB * 512)];   // prefetch next step

        const uint4* hb = (const uint4*)hbuf[t & 1];
        float p0 = 0.f, p1 = 0.f, p2 = 0.f, p3 = 0.f;   // 4 rotating chains
#pragma unroll
        for (int i = 0; i < 16; i++) {
            uint4 hh = hb[i];                            // broadcast read
            p0 = __builtin_amdgcn_fdot2(__builtin_bit_cast(f16x2, hh.x),
                                        __builtin_bit_cast(f16x2, w[4 * i + 0]), p0, false);
            p1 = __builtin_amdgcn_fdot2(__builtin_bit_cast(f16x2, hh.y),
                                        __builtin_bit_cast(f16x2, w[4 * i + 1]), p1, false);
            p2 = __builtin_amdgcn_fdot2(__builtin_bit_cast(f16x2, hh.z),
                                        __builtin_bit_cast(f16x2, w[4 * i + 2]), p2, false);
            p3 = __builtin_amdgcn_fdot2(__builtin_bit_cast(f16x2, hh.w),
                                        __builtin_bit_cast(f16x2, w[4 * i + 3]), p3, false);
        }
        float sg = ((p0 + p1) + (p2 + p3)) + xv;

        // quad butterfly: for g==0 lane, sg=i, a1=f, a2=g~, a3=o
        float a1 = __shfl_xor(sg, 1, 64);
        float a2 = __shfl_xor(sg, 2, 64);
        float a3 = __shfl_xor(a1, 2, 64);
        if (g == 0) {
            c = fmaf(sig_fast(a1), c, sig_fast(sg) * tanh_fast(a2));
            float h = sig_fast(a3) * tanh_fast(c);
            hbuf[(t + 1) & 1][u] = __builtin_bit_cast(u16, (f16)h);
            hop[(size_t)s * DD] = f2b(h);
        }
        __syncthreads();
        s = s_next;
    }
}

// ---------------------------------------------------------------------------
// V transpose: v[b][s][d] -> vT[b][d][s] via LDS tiles (64x64)
// ---------------------------------------------------------------------------
__global__ __launch_bounds__(256) void transpose_v(
    const u16* __restrict__ v, u16* __restrict__ vT)
{
    __shared__ u16 tile[64 * 72];
    const int b = blockIdx.z, s0 = blockIdx.x * 64, d0 = blockIdx.y * 64;
    const int tid = threadIdx.x;
#pragma unroll
    for (int i = 0; i < 2; i++) {
        int c = tid + 256 * i;
        int sl = c >> 3, dc = (c & 7) * 8;
        *(uint4*)&tile[sl * 72 + dc] =
            *(const uint4*)&v[((size_t)b * SS + s0 + sl) * DD + d0 + dc];
    }
    __syncthreads();
#pragma unroll
    for (int i = 0; i < 2; i++) {
        int c = tid + 256 * i;
        int dl = c >> 3, sc = (c & 7) * 8;
        u32 x0 = (u32)tile[(sc + 0) * 72 + dl] | ((u32)tile[(sc + 1) * 72 + dl] << 16);
        u32 x1 = (u32)tile[(sc + 2) * 72 + dl] | ((u32)tile[(sc + 3) * 72 + dl] << 16);
        u32 x2 = (u32)tile[(sc + 4) * 72 + dl] | ((u32)tile[(sc + 5) * 72 + dl] << 16);
        u32 x3 = (u32)tile[(sc + 6) * 72 + dl] | ((u32)tile[(sc + 7) * 72 + dl] << 16);
        uint4 val; val.x = x0; val.y = x1; val.z = x2; val.w = x3;
        *(uint4*)&vT[((size_t)b * DD + d0 + dl) * SS + s0 + sc] = val;
    }
}

// ---------------------------------------------------------------------------
// Flash attention: WG = (batch, 64-row q tile), 256 thr = 4 waves, each wave
// a 16-row stripe. KV tiles of 32. exp2-domain softmax, scale folded. f32 out.
// ---------------------------------------------------------------------------
__global__ __launch_bounds__(256) void attn_kernel(
    const u16* __restrict__ q, const u16* __restrict__ k,
    const u16* __restrict__ vT, float* __restrict__ out)
{
    __shared__ u16 Ks[32 * 264];
    __shared__ u16 Vs[256 * 40];
    __shared__ u16 Ps[64 * 40];
    const int b = blockIdx.y, q0 = blockIdx.x * 64;
    const int tid = threadIdx.x, wave = tid >> 6, lane = tid & 63;
    const int lo = lane & 15, hi = lane >> 4;
    const float c1 = 0.09016844005556021f;  // log2(e)/16

    bf16x8 qf[8];
    {
        const u16* qp = q + ((size_t)b * SS + q0 + wave * 16 + lo) * DD;
#pragma unroll
        for (int ks = 0; ks < 8; ks++)
            qf[ks] = *(const bf16x8a*)&qp[ks * 32 + hi * 8];
    }
    float m_i[4] = {-1e30f, -1e30f, -1e30f, -1e30f};
    float l_i[4] = {0.f, 0.f, 0.f, 0.f};
    f32x4 o[16] = {};

    for (int t0 = 0; t0 < SS; t0 += 32) {
        __syncthreads();
#pragma unroll
        for (int i = 0; i < 4; i++) {
            int c = tid + 256 * i;
            {
                int row = c >> 5, dc = (c & 31) * 8;
                *(uint4*)&Ks[row * 264 + dc] =
                    *(const uint4*)&k[((size_t)b * SS + t0 + row) * DD + dc];
            }
            {
                int d = c >> 2, sc = (c & 3) * 8;
                *(uint4*)&Vs[d * 40 + sc] =
                    *(const uint4*)&vT[((size_t)b * DD + d) * SS + t0 + sc];
            }
        }
        __syncthreads();

        f32x4 sacc[2] = {};
#pragma unroll
        for (int ks = 0; ks < 8; ks++) {
#pragma unroll
            for (int j = 0; j < 2; j++) {
                bf16x8 bfr = *(const bf16x8a*)&Ks[(j * 16 + lo) * 264 + ks * 32 + hi * 8];
                sacc[j] = __builtin_amdgcn_mfma_f32_16x16x32_bf16(qf[ks], bfr, sacc[j], 0, 0, 0);
            }
        }

        float tt[2][4];
#pragma unroll
        for (int j = 0; j < 2; j++)
#pragma unroll
            for (int r = 0; r < 4; r++) tt[j][r] = sacc[j][r] * c1;
        float rm[4];
#pragma unroll
        for (int r = 0; r < 4; r++) rm[r] = fmaxf(tt[0][r], tt[1][r]);
#pragma unroll
        for (int mm = 1; mm <= 8; mm <<= 1)
#pragma unroll
            for (int r = 0; r < 4; r++) rm[r] = fmaxf(rm[r], __shfl_xor(rm[r], mm, 64));
        float al[4], rs[4];
#pragma unroll
        for (int r = 0; r < 4; r++) {
            float mn = fmaxf(m_i[r], rm[r]);
            al[r] = __builtin_amdgcn_exp2f(m_i[r] - mn);
            m_i[r] = mn;
            rs[r] = 0.f;
        }
#pragma unroll
        for (int j = 0; j < 2; j++)
#pragma unroll
            for (int r = 0; r < 4; r++) {
                float p = __builtin_amdgcn_exp2f(tt[j][r] - m_i[r]);
                rs[r] += p;
                Ps[(wave * 16 + hi * 4 + r) * 40 + j * 16 + lo] = f2b(p);
            }
#pragma unroll
        for (int mm = 1; mm <= 8; mm <<= 1)
#pragma unroll
            for (int r = 0; r < 4; r++) rs[r] += __shfl_xor(rs[r], mm, 64);
#pragma unroll
        for (int r = 0; r < 4; r++) l_i[r] = l_i[r] * al[r] + rs[r];
#pragma unroll
        for (int nt = 0; nt < 16; nt++) {
            o[nt][0] *= al[0]; o[nt][1] *= al[1];
            o[nt][2] *= al[2]; o[nt][3] *= al[3];
        }
        __syncthreads();   // order u16 Ps stores vs vector reload
        bf16x8 pa = *(const bf16x8a*)&Ps[(wave * 16 + lo) * 40 + hi * 8];
#pragma unroll
        for (int nt = 0; nt < 16; nt++) {
            bf16x8 bv = *(const bf16x8a*)&Vs[(nt * 16 + lo) * 40 + hi * 8];
            o[nt] = __builtin_amdgcn_mfma_f32_16x16x32_bf16(pa, bv, o[nt], 0, 0, 0);
        }
    }
    float inv[4];
#pragma unroll
    for (int r = 0; r < 4; r++) inv[r] = __builtin_amdgcn_rcpf(l_i[r]);
#pragma unroll
    for (int nt = 0; nt < 16; nt++)
#pragma unroll
        for (int r = 0; r < 4; r++) {
            int row = q0 + wave * 16 + hi * 4 + r;
            int col = nt * 16 + lo;
            out[((size_t)b * SS + row) * DD + col] = o[nt][r] * inv[r];
        }
}

// ---------------------------------------------------------------------------
extern "C" void kernel_launch(void* const* d_in, const int* in_sizes, int n_in,
                              void* d_out, int out_size, void* d_ws, size_t ws_size,
                              hipStream_t stream)
{
    (void)in_sizes; (void)n_in; (void)out_size;
    const float* x      = (const float*)d_in[0];
    const float* fw_Wih = (const float*)d_in[1];
    const float* fw_Whh = (const float*)d_in[2];
    const float* fw_bih = (const float*)d_in[3];
    const float* fw_bhh = (const float*)d_in[4];
    const float* bw_Wih = (const float*)d_in[5];
    const float* bw_Whh = (const float*)d_in[6];
    const float* bw_bih = (const float*)d_in[7];
    const float* bw_bhh = (const float*)d_in[8];
    const float* Wq = (const float*)d_in[9];
    const float* Wk = (const float*)d_in[10];
    const float* Wv = (const float*)d_in[11];

    // Workspace layout (total 143,523,840 B; ws proven >= 201 MB in r1/r2):
    //   [0, 67108864)    xg bf16 [2][S][B][512], cols gate-interleaved
    //                    (dead after scan; vb aliases)
    //   +67108864        h   bf16 [32768][256]
    //   +83886080        qb   +100663296 kb   +117440512 vT
    //   +142606336       weights: fwWih_p, bwWih_p, wq, wk, wv (bf16),
    //                    Whh f16 permuted [2][512][128]
    if (ws_size < 143523840ULL) return;

    char* ws = (char*)d_ws;
    u16* xg  = (u16*)ws;
    u16* h   = (u16*)(ws + 67108864);
    u16* qb  = (u16*)(ws + 83886080);
    u16* kb  = (u16*)(ws + 100663296);
    u16* vT  = (u16*)(ws + 117440512);
    u16* wfih16 = (u16*)(ws + 142606336);
    u16* wbih16 = (u16*)(ws + 142606336 + 131072);
    u16* wq16   = (u16*)(ws + 142606336 + 262144);
    u16* wk16   = (u16*)(ws + 142606336 + 393216);
    u16* wv16   = (u16*)(ws + 142606336 + 524288);
    u16* whhf16 = (u16*)(ws + 142606336 + 655360);   // [2][512][128] f16
    u16* vb = (u16*)ws;                              // aliases xg (dead after scan)

    conv_weights<<<dim3(32, 7), 256, 0, stream>>>(
        fw_Wih, bw_Wih, fw_Whh, bw_Whh, Wq, Wk, Wv,
        wfih16, wbih16, whhf16, wq16, wk16, wv16);

    // xg = x @ Wih_p^T + biases -> [s][b][512] permuted-col layout (both dirs);
    // x is fp32, converted to bf16 during LDS staging
    gemm_xg<<<dim3(256, 4, 2), 256, 0, stream>>>(
        x, wfih16, wbih16, fw_bih, fw_bhh, bw_bih, bw_bhh, xg);
    // dot2 scan, 64 WGs x 512 thr -> h [b][s][256]
    lstm_scan_512<<<64, 512, 0, stream>>>(whhf16, xg, h);
    // q,k,v projections in one launch
    gemm_qkv<<<dim3(256, 2, 3), 256, 0, stream>>>(h, wq16, wk16, wv16, qb, kb, vb);
    transpose_v<<<dim3(16, 4, 32), 256, 0, stream>>>(vb, vT);
    // fused attention -> out fp32
    attn_kernel<<<dim3(16, 32), 256, 0, stream>>>(qb, kb, vT, (float*)d_out);
}

// Round 8
// 837.139 us; speedup vs baseline: 1.4411x; 1.0743x over previous
//
#include <hip/hip_runtime.h>

typedef unsigned short u16;
typedef unsigned int u32;
typedef __bf16 bf16x8 __attribute__((ext_vector_type(8)));
typedef bf16x8 __attribute__((may_alias)) bf16x8a;   // TBAA-safe vector loads
typedef float f32x4 __attribute__((ext_vector_type(4)));
typedef _Float16 f16;
typedef _Float16 f16x2 __attribute__((ext_vector_type(2)));

#define BB 32
#define SS 1024
#define HH 128
#define DD 256

__device__ __forceinline__ float b2f(u16 u) {
    u32 v = ((u32)u) << 16;
    return __builtin_bit_cast(float, v);
}
__device__ __forceinline__ u16 f2b(float f) {
    u32 u = __builtin_bit_cast(u32, f);
    u32 r = (u + 0x7fffu + ((u >> 16) & 1u)) >> 16;   // RNE
    return (u16)r;
}
__device__ __forceinline__ float sig_fast(float x) {
    return __builtin_amdgcn_rcpf(1.0f + __builtin_amdgcn_exp2f(-1.4426950408889634f * x));
}
__device__ __forceinline__ float tanh_fast(float x) {
    return 2.0f * sig_fast(2.0f * x) - 1.0f;
}

// ---------------------------------------------------------------------------
// All 7 weight conversions in ONE kernel (each matrix = 65536 elements).
// mode 0: gate-perm (row g*128+u -> u*4+g), bf16   (Wih for xg GEMM)
// mode 1: gate-perm, f16                           (Whh for scan dot2)
// mode 2: plain, bf16                              (Wq/Wk/Wv)
// ---------------------------------------------------------------------------
__global__ __launch_bounds__(256) void conv_weights(
    const float* __restrict__ fwWih, const float* __restrict__ bwWih,
    const float* __restrict__ fwWhh, const float* __restrict__ bwWhh,
    const float* __restrict__ Wq, const float* __restrict__ Wk,
    const float* __restrict__ Wv,
    u16* __restrict__ wfih, u16* __restrict__ wbih, u16* __restrict__ whhf,
    u16* __restrict__ wq, u16* __restrict__ wk, u16* __restrict__ wv)
{
    const int which = blockIdx.y;
    const float* src; u16* dst; int mode;
    switch (which) {
        case 0: src = fwWih; dst = wfih;              mode = 0; break;
        case 1: src = bwWih; dst = wbih;              mode = 0; break;
        case 2: src = fwWhh; dst = whhf;              mode = 1; break;
        case 3: src = bwWhh; dst = whhf + 512 * 128;  mode = 1; break;
        case 4: src = Wq;    dst = wq;                mode = 2; break;
        case 5: src = Wk;    dst = wk;                mode = 2; break;
        default: src = Wv;   dst = wv;                mode = 2; break;
    }
    for (int i = blockIdx.x * 256 + threadIdx.x; i < 65536 / 4; i += 32 * 256) {
        float4 v = ((const float4*)src)[i];
        ushort4 o;
        if (mode == 1) {
            o.x = __builtin_bit_cast(u16, (f16)v.x);
            o.y = __builtin_bit_cast(u16, (f16)v.y);
            o.z = __builtin_bit_cast(u16, (f16)v.z);
            o.w = __builtin_bit_cast(u16, (f16)v.w);
        } else {
            o.x = f2b(v.x); o.y = f2b(v.y); o.z = f2b(v.z); o.w = f2b(v.w);
        }
        if (mode == 2) {
            ((ushort4*)dst)[i] = o;
        } else {
            int r = i >> 5, c4 = i & 31;                 // [512][128] view
            int rp = ((r & 127) << 2) | (r >> 7);        // u*4 + g
            *(ushort4*)&dst[rp * 128 + c4 * 4] = o;
        }
    }
}

// ---------------------------------------------------------------------------
// Shared MFMA GEMM core: C[M,N] = A[M,K]*Bt[N,K]^T, fp32 acc, bf16 out.
// 128x128 tile, BK=64, 256 thr = 4 waves (2x2), wave = 64x64.
// AFP32: A is fp32 in global, converted to bf16 during LDS staging.
// MODE 0: row-major store, no bias. MODE 1: xg store [s][b][col] + bias
// (bias index un-permuted since cols are gate-interleaved).
// ---------------------------------------------------------------------------
template <int MODE, int AFP32>
__device__ __forceinline__ void gemm_core(
    const void* __restrict__ Araw, const u16* __restrict__ Bt,
    const float* __restrict__ bias1, const float* __restrict__ bias2,
    u16* __restrict__ Cout, int K, int N)
{
    __shared__ u16 As[128 * 72];
    __shared__ u16 Bs[128 * 72];
    const int tid = threadIdx.x;
    const int lane = tid & 63, wave = tid >> 6;
    const int wm = wave >> 1, wn = wave & 1;
    const int lo = lane & 15, hi = lane >> 4;
    const int m0 = blockIdx.x * 128, n0 = blockIdx.y * 128;

    f32x4 acc[4][4] = {};

    for (int k0 = 0; k0 < K; k0 += 64) {
        __syncthreads();
#pragma unroll
        for (int i = 0; i < 4; i++) {
            int c = tid + 256 * i;
            int row = c >> 3, kc = (c & 7) * 8;
            if (AFP32) {
                const float* ap = (const float*)Araw + (size_t)(m0 + row) * K + k0 + kc;
                float4 v0 = *(const float4*)ap;
                float4 v1 = *(const float4*)(ap + 4);
                uint4 o;
                o.x = (u32)f2b(v0.x) | ((u32)f2b(v0.y) << 16);
                o.y = (u32)f2b(v0.z) | ((u32)f2b(v0.w) << 16);
                o.z = (u32)f2b(v1.x) | ((u32)f2b(v1.y) << 16);
                o.w = (u32)f2b(v1.z) | ((u32)f2b(v1.w) << 16);
                *(uint4*)&As[row * 72 + kc] = o;
            } else {
                *(uint4*)&As[row * 72 + kc] =
                    *(const uint4*)&((const u16*)Araw)[(size_t)(m0 + row) * K + k0 + kc];
            }
            *(uint4*)&Bs[row * 72 + kc] =
                *(const uint4*)&Bt[(size_t)(n0 + row) * K + k0 + kc];
        }
        __syncthreads();
#pragma unroll
        for (int ks = 0; ks < 2; ks++) {
            bf16x8 af[4], bfr[4];
#pragma unroll
            for (int i = 0; i < 4; i++)
                af[i] = *(const bf16x8a*)&As[(wm * 64 + i * 16 + lo) * 72 + ks * 32 + hi * 8];
#pragma unroll
            for (int j = 0; j < 4; j++)
                bfr[j] = *(const bf16x8a*)&Bs[(wn * 64 + j * 16 + lo) * 72 + ks * 32 + hi * 8];
#pragma unroll
            for (int i = 0; i < 4; i++)
#pragma unroll
                for (int j = 0; j < 4; j++)
                    acc[i][j] = __builtin_amdgcn_mfma_f32_16x16x32_bf16(
                        af[i], bfr[j], acc[i][j], 0, 0, 0);
        }
    }
#pragma unroll
    for (int j = 0; j < 4; j++) {
        int col = n0 + wn * 64 + j * 16 + lo;
        float bsum = 0.f;
        if (MODE == 1) {
            int co = ((col & 3) << 7) | (col >> 2);   // un-permute for bias lookup
            bsum = bias1[co] + bias2[co];
        }
#pragma unroll
        for (int i = 0; i < 4; i++) {
            int row0 = m0 + wm * 64 + i * 16 + hi * 4;
#pragma unroll
            for (int r = 0; r < 4; r++) {
                float v = acc[i][j][r] + bsum;
                if (MODE == 1) {
                    int row = row0 + r;                 // = b*1024 + s
                    int sidx = row & 1023, bidx = row >> 10;
                    Cout[(size_t)sidx * (BB * 512) + bidx * 512 + col] = f2b(v);
                } else {
                    Cout[(size_t)(row0 + r) * N + col] = f2b(v);
                }
            }
        }
    }
}

// both xg directions in one launch (blockIdx.z = dir); A = x in fp32
__global__ __launch_bounds__(256) void gemm_xg(
    const float* __restrict__ A, const u16* __restrict__ Bt_f,
    const u16* __restrict__ Bt_b,
    const float* __restrict__ f_bih, const float* __restrict__ f_bhh,
    const float* __restrict__ b_bih, const float* __restrict__ b_bhh,
    u16* __restrict__ xg)
{
    const int dir = blockIdx.z;
    gemm_core<1, 1>(A, dir ? Bt_b : Bt_f,
                    dir ? b_bih : f_bih, dir ? b_bhh : f_bhh,
                    xg + (size_t)dir * SS * BB * 512, 128, 512);
}

// q,k,v in one launch (blockIdx.z selects)
__global__ __launch_bounds__(256) void gemm_qkv(
    const u16* __restrict__ A, const u16* __restrict__ Wq,
    const u16* __restrict__ Wk, const u16* __restrict__ Wv,
    u16* __restrict__ qb, u16* __restrict__ kb, u16* __restrict__ vb)
{
    const int z = blockIdx.z;
    const u16* Bt = (z == 0) ? Wq : (z == 1) ? Wk : Wv;
    u16* out = (z == 0) ? qb : (z == 1) ? kb : vb;
    gemm_core<0, 0>(A, Bt, nullptr, nullptr, out, 256, 256);
}

// ---------------------------------------------------------------------------
// Split-K dot2 LSTM scan: 64 WGs (one per (dir,b) sequence), 256 thr = 4
// waves (1/SIMD). Thread t: unit u = t>>1 owns ALL 4 permuted gate rows
// 4u..4u+3 (no gate shuffle), K-half kh = t&1 (halves LDS h traffic).
// Weights loaded ONCE through a VOLATILE pointer -> cannot be rematerialized
// into the loop -> guaranteed VGPR-resident (r5-r7 postmortem: compiler
// folded weight loads into the loop, re-reading 128 KB/CU/step from L1/L2 =
// the ~1550 cyc step-time wall; VGPR_Count 44-88 < weight footprint was the
// tell). h in LDS f16, double-buffered, 2-way-broadcast reads (free).
// Cross-half reduce: 4x shfl_xor(1). One barrier/step.
// ---------------------------------------------------------------------------
__global__ __launch_bounds__(256, 1) void lstm_scan_sk(
    const u16* __restrict__ Whh_h,   // [2][512][128] f16, rows permuted
    const u16* __restrict__ xg,      // [2][S][B][512] bf16, cols permuted
    u16* __restrict__ hout)          // [B][S][256] bf16
{
    const int wg = blockIdx.x;       // 0..63
    const int dir = wg >> 5, b = wg & 31;
    const int t_ = threadIdx.x;      // 0..255
    const int u = t_ >> 1;           // unit 0..127
    const int kh = t_ & 1;           // K-half

    // resident weights: rows 4u..4u+3, K-half kh -> 128 u32 in VGPRs.
    u32 w[4][32];
    {
        const volatile u32* vp = (const volatile u32*)(Whh_h + (size_t)dir * 512 * 128);
#pragma unroll
        for (int g = 0; g < 4; g++) {
            int base = ((4 * u + g) * 128 + kh * 64) >> 1;   // u32 index
#pragma unroll
            for (int k = 0; k < 32; k++) w[g][k] = vp[base + k];
        }
    }

    __shared__ __align__(16) u16 hbuf[2][128];   // f16 bits, double-buffered
    if (t_ < 128) hbuf[0][t_] = 0;
    float c = 0.0f;

    const u16* xgp = xg + (size_t)dir * SS * (BB * 512) + (size_t)b * 512 + 4 * u;
    u16* hop = hout + (size_t)b * SS * DD + dir * HH + u;

    int s = dir ? (SS - 1) : 0;
    const int dstep = dir ? -1 : 1;
    uint2 nx = *(const uint2*)&xgp[(size_t)s * (BB * 512)];
    __syncthreads();

    for (int t = 0; t < SS; t++) {
        uint2 xv = nx;
        int s_next = s + dstep;
        if (t < SS - 1)
            nx = *(const uint2*)&xgp[(size_t)s_next * (BB * 512)];  // prefetch

        const uint4* hb = (const uint4*)&hbuf[t & 1][kh * 64];
        float g0 = 0.f, g1 = 0.f, g2 = 0.f, g3 = 0.f;   // 4 chains (one per gate)
#pragma unroll
        for (int cc = 0; cc < 8; cc++) {
            uint4 hh = hb[cc];                           // 2-way broadcast (free)
            u32 hv[4] = {hh.x, hh.y, hh.z, hh.w};
#pragma unroll
            for (int j = 0; j < 4; j++) {
                f16x2 hp = __builtin_bit_cast(f16x2, hv[j]);
                g0 = __builtin_amdgcn_fdot2(hp, __builtin_bit_cast(f16x2, w[0][4 * cc + j]), g0, false);
                g1 = __builtin_amdgcn_fdot2(hp, __builtin_bit_cast(f16x2, w[1][4 * cc + j]), g1, false);
                g2 = __builtin_amdgcn_fdot2(hp, __builtin_bit_cast(f16x2, w[2][4 * cc + j]), g2, false);
                g3 = __builtin_amdgcn_fdot2(hp, __builtin_bit_cast(f16x2, w[3][4 * cc + j]), g3, false);
            }
        }
        // cross-half reduce (partner lane has the other K-half)
        g0 += __shfl_xor(g0, 1, 64);
        g1 += __shfl_xor(g1, 1, 64);
        g2 += __shfl_xor(g2, 1, 64);
        g3 += __shfl_xor(g3, 1, 64);
        // add xg (gates i,f,g~,o = permuted cols 4u..4u+3)
        g0 += b2f((u16)(xv.x & 0xffff)); g1 += b2f((u16)(xv.x >> 16));
        g2 += b2f((u16)(xv.y & 0xffff)); g3 += b2f((u16)(xv.y >> 16));

        c = fmaf(sig_fast(g1), c, sig_fast(g0) * tanh_fast(g2));
        float h = sig_fast(g3) * tanh_fast(c);

        if (kh == 0)
            hbuf[(t + 1) & 1][u] = __builtin_bit_cast(u16, (f16)h);
        else
            hop[(size_t)s * DD] = f2b(h);
        __syncthreads();
        s = s_next;
    }
}

// ---------------------------------------------------------------------------
// V transpose: v[b][s][d] -> vT[b][d][s] via LDS tiles (64x64)
// ---------------------------------------------------------------------------
__global__ __launch_bounds__(256) void transpose_v(
    const u16* __restrict__ v, u16* __restrict__ vT)
{
    __shared__ u16 tile[64 * 72];
    const int b = blockIdx.z, s0 = blockIdx.x * 64, d0 = blockIdx.y * 64;
    const int tid = threadIdx.x;
#pragma unroll
    for (int i = 0; i < 2; i++) {
        int c = tid + 256 * i;
        int sl = c >> 3, dc = (c & 7) * 8;
        *(uint4*)&tile[sl * 72 + dc] =
            *(const uint4*)&v[((size_t)b * SS + s0 + sl) * DD + d0 + dc];
    }
    __syncthreads();
#pragma unroll
    for (int i = 0; i < 2; i++) {
        int c = tid + 256 * i;
        int dl = c >> 3, sc = (c & 7) * 8;
        u32 x0 = (u32)tile[(sc + 0) * 72 + dl] | ((u32)tile[(sc + 1) * 72 + dl] << 16);
        u32 x1 = (u32)tile[(sc + 2) * 72 + dl] | ((u32)tile[(sc + 3) * 72 + dl] << 16);
        u32 x2 = (u32)tile[(sc + 4) * 72 + dl] | ((u32)tile[(sc + 5) * 72 + dl] << 16);
        u32 x3 = (u32)tile[(sc + 6) * 72 + dl] | ((u32)tile[(sc + 7) * 72 + dl] << 16);
        uint4 val; val.x = x0; val.y = x1; val.z = x2; val.w = x3;
        *(uint4*)&vT[((size_t)b * DD + d0 + dl) * SS + s0 + sc] = val;
    }
}

// ---------------------------------------------------------------------------
// Flash attention: WG = (batch, 64-row q tile), 256 thr = 4 waves, each wave
// a 16-row stripe. KV tiles of 32. exp2-domain softmax, scale folded. f32 out.
// ---------------------------------------------------------------------------
__global__ __launch_bounds__(256) void attn_kernel(
    const u16* __restrict__ q, const u16* __restrict__ k,
    const u16* __restrict__ vT, float* __restrict__ out)
{
    __shared__ u16 Ks[32 * 264];
    __shared__ u16 Vs[256 * 40];
    __shared__ u16 Ps[64 * 40];
    const int b = blockIdx.y, q0 = blockIdx.x * 64;
    const int tid = threadIdx.x, wave = tid >> 6, lane = tid & 63;
    const int lo = lane & 15, hi = lane >> 4;
    const float c1 = 0.09016844005556021f;  // log2(e)/16

    bf16x8 qf[8];
    {
        const u16* qp = q + ((size_t)b * SS + q0 + wave * 16 + lo) * DD;
#pragma unroll
        for (int ks = 0; ks < 8; ks++)
            qf[ks] = *(const bf16x8a*)&qp[ks * 32 + hi * 8];
    }
    float m_i[4] = {-1e30f, -1e30f, -1e30f, -1e30f};
    float l_i[4] = {0.f, 0.f, 0.f, 0.f};
    f32x4 o[16] = {};

    for (int t0 = 0; t0 < SS; t0 += 32) {
        __syncthreads();
#pragma unroll
        for (int i = 0; i < 4; i++) {
            int c = tid + 256 * i;
            {
                int row = c >> 5, dc = (c & 31) * 8;
                *(uint4*)&Ks[row * 264 + dc] =
                    *(const uint4*)&k[((size_t)b * SS + t0 + row) * DD + dc];
            }
            {
                int d = c >> 2, sc = (c & 3) * 8;
                *(uint4*)&Vs[d * 40 + sc] =
                    *(const uint4*)&vT[((size_t)b * DD + d) * SS + t0 + sc];
            }
        }
        __syncthreads();

        f32x4 sacc[2] = {};
#pragma unroll
        for (int ks = 0; ks < 8; ks++) {
#pragma unroll
            for (int j = 0; j < 2; j++) {
                bf16x8 bfr = *(const bf16x8a*)&Ks[(j * 16 + lo) * 264 + ks * 32 + hi * 8];
                sacc[j] = __builtin_amdgcn_mfma_f32_16x16x32_bf16(qf[ks], bfr, sacc[j], 0, 0, 0);
            }
        }

        float tt[2][4];
#pragma unroll
        for (int j = 0; j < 2; j++)
#pragma unroll
            for (int r = 0; r < 4; r++) tt[j][r] = sacc[j][r] * c1;
        float rm[4];
#pragma unroll
        for (int r = 0; r < 4; r++) rm[r] = fmaxf(tt[0][r], tt[1][r]);
#pragma unroll
        for (int mm = 1; mm <= 8; mm <<= 1)
#pragma unroll
            for (int r = 0; r < 4; r++) rm[r] = fmaxf(rm[r], __shfl_xor(rm[r], mm, 64));
        float al[4], rs[4];
#pragma unroll
        for (int r = 0; r < 4; r++) {
            float mn = fmaxf(m_i[r], rm[r]);
            al[r] = __builtin_amdgcn_exp2f(m_i[r] - mn);
            m_i[r] = mn;
            rs[r] = 0.f;
        }
#pragma unroll
        for (int j = 0; j < 2; j++)
#pragma unroll
            for (int r = 0; r < 4; r++) {
                float p = __builtin_amdgcn_exp2f(tt[j][r] - m_i[r]);
                rs[r] += p;
                Ps[(wave * 16 + hi * 4 + r) * 40 + j * 16 + lo] = f2b(p);
            }
#pragma unroll
        for (int mm = 1; mm <= 8; mm <<= 1)
#pragma unroll
            for (int r = 0; r < 4; r++) rs[r] += __shfl_xor(rs[r], mm, 64);
#pragma unroll
        for (int r = 0; r < 4; r++) l_i[r] = l_i[r] * al[r] + rs[r];
#pragma unroll
        for (int nt = 0; nt < 16; nt++) {
            o[nt][0] *= al[0]; o[nt][1] *= al[1];
            o[nt][2] *= al[2]; o[nt][3] *= al[3];
        }
        __syncthreads();   // order u16 Ps stores vs vector reload
        bf16x8 pa = *(const bf16x8a*)&Ps[(wave * 16 + lo) * 40 + hi * 8];
#pragma unroll
        for (int nt = 0; nt < 16; nt++) {
            bf16x8 bv = *(const bf16x8a*)&Vs[(nt * 16 + lo) * 40 + hi * 8];
            o[nt] = __builtin_amdgcn_mfma_f32_16x16x32_bf16(pa, bv, o[nt], 0, 0, 0);
        }
    }
    float inv[4];
#pragma unroll
    for (int r = 0; r < 4; r++) inv[r] = __builtin_amdgcn_rcpf(l_i[r]);
#pragma unroll
    for (int nt = 0; nt < 16; nt++)
#pragma unroll
        for (int r = 0; r < 4; r++) {
            int row = q0 + wave * 16 + hi * 4 + r;
            int col = nt * 16 + lo;
            out[((size_t)b * SS + row) * DD + col] = o[nt][r] * inv[r];
        }
}

// ---------------------------------------------------------------------------
extern "C" void kernel_launch(void* const* d_in, const int* in_sizes, int n_in,
                              void* d_out, int out_size, void* d_ws, size_t ws_size,
                              hipStream_t stream)
{
    (void)in_sizes; (void)n_in; (void)out_size;
    const float* x      = (const float*)d_in[0];
    const float* fw_Wih = (const float*)d_in[1];
    const float* fw_Whh = (const float*)d_in[2];
    const float* fw_bih = (const float*)d_in[3];
    const float* fw_bhh = (const float*)d_in[4];
    const float* bw_Wih = (const float*)d_in[5];
    const float* bw_Whh = (const float*)d_in[6];
    const float* bw_bih = (const float*)d_in[7];
    const float* bw_bhh = (const float*)d_in[8];
    const float* Wq = (const float*)d_in[9];
    const float* Wk = (const float*)d_in[10];
    const float* Wv = (const float*)d_in[11];

    // Workspace layout (total 143,523,840 B; ws proven >= 201 MB in r1/r2):
    //   [0, 67108864)    xg bf16 [2][S][B][512], cols gate-interleaved
    //                    (dead after scan; vb aliases)
    //   +67108864        h   bf16 [32768][256]
    //   +83886080        qb   +100663296 kb   +117440512 vT
    //   +142606336       weights: fwWih_p, bwWih_p, wq, wk, wv (bf16),
    //                    Whh f16 permuted [2][512][128]
    if (ws_size < 143523840ULL) return;

    char* ws = (char*)d_ws;
    u16* xg  = (u16*)ws;
    u16* h   = (u16*)(ws + 67108864);
    u16* qb  = (u16*)(ws + 83886080);
    u16* kb  = (u16*)(ws + 100663296);
    u16* vT  = (u16*)(ws + 117440512);
    u16* wfih16 = (u16*)(ws + 142606336);
    u16* wbih16 = (u16*)(ws + 142606336 + 131072);
    u16* wq16   = (u16*)(ws + 142606336 + 262144);
    u16* wk16   = (u16*)(ws + 142606336 + 393216);
    u16* wv16   = (u16*)(ws + 142606336 + 524288);
    u16* whhf16 = (u16*)(ws + 142606336 + 655360);   // [2][512][128] f16
    u16* vb = (u16*)ws;                              // aliases xg (dead after scan)

    conv_weights<<<dim3(32, 7), 256, 0, stream>>>(
        fw_Wih, bw_Wih, fw_Whh, bw_Whh, Wq, Wk, Wv,
        wfih16, wbih16, whhf16, wq16, wk16, wv16);

    // xg = x @ Wih_p^T + biases -> [s][b][512] permuted-col layout (both dirs);
    // x is fp32, converted to bf16 during LDS staging
    gemm_xg<<<dim3(256, 4, 2), 256, 0, stream>>>(
        x, wfih16, wbih16, fw_bih, fw_bhh, bw_bih, bw_bhh, xg);
    // split-K dot2 scan, 64 WGs x 256 thr -> h [b][s][256]
    lstm_scan_sk<<<64, 256, 0, stream>>>(whhf16, xg, h);
    // q,k,v projections in one launch
    gemm_qkv<<<dim3(256, 2, 3), 256, 0, stream>>>(h, wq16, wk16, wv16, qb, kb, vb);
    transpose_v<<<dim3(16, 4, 32), 256, 0, stream>>>(vb, vT);
    // fused attention -> out fp32
    attn_kernel<<<dim3(16, 32), 256, 0, stream>>>(qb, kb, vT, (float*)d_out);
}